// Round 2
// baseline (163.469 us; speedup 1.0000x reference)
//
#include <hip/hip_runtime.h>
#include <hip/hip_bf16.h>

#define N_CELLS 50000
#define DEG 32
#define DIM 64
#define NEG_SLOPE 0.2

// Kernel A: ns[r] = x[r] . (W0 @ a_src), nd[r] = x[r] . (W0 @ a_dst), f64 chain.
// One wave per row iteration; lane = feature index.
__global__ void gat_nodes(const float* __restrict__ x,
                          const float* __restrict__ W0,
                          const float* __restrict__ a0,
                          double* __restrict__ ns,
                          double* __restrict__ nd) {
  const int lane = threadIdx.x & 63;
  const int gwave = (blockIdx.x * blockDim.x + threadIdx.x) >> 6;
  const int nwaves = (gridDim.x * blockDim.x) >> 6;

  // p_src[i] = sum_o W0[i][o] * a_src[o]  (node_src = x @ (W0 @ a_src))
  double ps = 0.0, pd = 0.0;
  for (int o = 0; o < DIM; ++o) {
    double w = (double)W0[lane * DIM + o];
    ps = fma(w, (double)a0[o], ps);
    pd = fma(w, (double)a0[DIM + o], pd);
  }

  for (int r = gwave; r < N_CELLS; r += nwaves) {
    double xv = (double)x[r * DIM + lane];
    double s = xv * ps;
    double d = xv * pd;
#pragma unroll
    for (int m = 32; m >= 1; m >>= 1) {
      s += __shfl_xor(s, m, 64);
      d += __shfl_xor(d, m, 64);
    }
    if (lane == 0) {
      ns[r] = s;
      nd[r] = d;
    }
  }
}

// Kernel B: per row r (one wave):
//   lanes 0..31: e_j = leaky(ns[r] + nd[col_j]) in f64; rs = sum e; w_j = nv_j*e_j/rs
//   all lanes:   h[lane] = sum_j w_j * x[col_j][lane]   (f32)
//   out[r][lane] = relu( sum_k h[k] * W0[k][lane] )     (f32)
__global__ __launch_bounds__(256)
void gat_edges(const float* __restrict__ x,
               const int* __restrict__ ecol,
               const float* __restrict__ nv,
               const float* __restrict__ W0,
               const double* __restrict__ ns,
               const double* __restrict__ nd,
               float* __restrict__ out) {
  __shared__ __align__(16) float w_s[4][DEG];
  __shared__ __align__(16) int c_s[4][DEG];
  __shared__ __align__(16) float h_s[4][DIM];

  const int lane = threadIdx.x & 63;
  const int wid = threadIdx.x >> 6;
  const int gwave = blockIdx.x * 4 + wid;
  const int nwaves = gridDim.x * 4;

  // W0 column `lane` in registers
  float w0c[DIM];
#pragma unroll
  for (int k = 0; k < DIM; ++k) w0c[k] = W0[k * DIM + lane];

  for (int r = gwave; r < N_CELLS; r += nwaves) {
    // ---- e phase (lanes 0..31), f64 ----
    double e = 0.0;
    int col = 0;
    float nvv = 0.0f;
    if (lane < DEG) {
      col = ecol[r * DEG + lane];
      nvv = nv[r * DEG + lane];
      double z = ns[r] + nd[col];
      e = (z >= 0.0) ? z : NEG_SLOPE * z;
    }
    double rs = e;
#pragma unroll
    for (int m = 16; m >= 1; m >>= 1) rs += __shfl_xor(rs, m, 64);
    if (lane < DEG) {
      w_s[wid][lane] = (float)((double)nvv * (e / rs));
      c_s[wid][lane] = col;
    }
    __asm__ volatile("s_waitcnt lgkmcnt(0)" ::: "memory");

    // ---- gather phase: h[lane] = sum_j w_j * x[col_j][lane] ----
    float acc = 0.0f;
    const int4* c4p = (const int4*)c_s[wid];
    const float4* w4p = (const float4*)w_s[wid];
#pragma unroll
    for (int q = 0; q < DEG / 4; ++q) {
      int4 c4 = c4p[q];
      float4 w4 = w4p[q];
      float x0 = x[(size_t)c4.x * DIM + lane];
      float x1 = x[(size_t)c4.y * DIM + lane];
      float x2 = x[(size_t)c4.z * DIM + lane];
      float x3 = x[(size_t)c4.w * DIM + lane];
      acc = fmaf(w4.x, x0, acc);
      acc = fmaf(w4.y, x1, acc);
      acc = fmaf(w4.z, x2, acc);
      acc = fmaf(w4.w, x3, acc);
    }
    __asm__ volatile("s_waitcnt lgkmcnt(0)" ::: "memory");
    h_s[wid][lane] = acc;
    __asm__ volatile("s_waitcnt lgkmcnt(0)" ::: "memory");

    // ---- final: out[r][lane] = relu( sum_k h[k] * W0[k][lane] ) ----
    float o = 0.0f;
    const float4* h4p = (const float4*)h_s[wid];
#pragma unroll
    for (int q = 0; q < DIM / 4; ++q) {
      float4 h4 = h4p[q];
      o = fmaf(h4.x, w0c[4 * q + 0], o);
      o = fmaf(h4.y, w0c[4 * q + 1], o);
      o = fmaf(h4.z, w0c[4 * q + 2], o);
      o = fmaf(h4.w, w0c[4 * q + 3], o);
    }
    o = fmaxf(o, 0.0f);
    out[r * DIM + lane] = o;
    __asm__ volatile("s_waitcnt lgkmcnt(0)" ::: "memory");
  }
}

extern "C" void kernel_launch(void* const* d_in, const int* in_sizes, int n_in,
                              void* d_out, int out_size, void* d_ws, size_t ws_size,
                              hipStream_t stream) {
  const float* x = (const float*)d_in[0];
  // d_in[1] = edge_rows: known structure repeat(arange(N_CELLS), DEG) — row = edge/DEG
  const int* ecol = (const int*)d_in[2];
  const float* nv = (const float*)d_in[3];
  const float* W0 = (const float*)d_in[4];
  const float* a0 = (const float*)d_in[5];
  float* out = (float*)d_out;

  double* ns = (double*)d_ws;            // 50000 f64
  double* nd = ns + N_CELLS;             // 50000 f64  (800 KB total)

  hipLaunchKernelGGL(gat_nodes, dim3(250), dim3(256), 0, stream, x, W0, a0, ns, nd);
  hipLaunchKernelGGL(gat_edges, dim3(1250), dim3(256), 0, stream,
                     x, ecol, nv, W0, ns, nd, out);
}

// Round 3
// 146.535 us; speedup vs baseline: 1.1156x; 1.1156x over previous
//
#include <hip/hip_runtime.h>
#include <hip/hip_bf16.h>

#define N_CELLS 50000
#define DEG 32
#define DIM 64
#define NEG_SLOPE 0.2

// Kernel A (thread-per-row): ns[r] = x[r].(W0@a_src), nd[r] = x[r].(W0@a_dst).
// p vectors (f64) staged in LDS once per block; broadcast reads are conflict-free.
__global__ __launch_bounds__(256)
void gat_nodes(const float* __restrict__ x,
               const float* __restrict__ W0,
               const float* __restrict__ a0,
               double* __restrict__ ns,
               double* __restrict__ nd) {
  __shared__ double2 p_s[DIM];  // (p_src[i], p_dst[i])

  const int tid = threadIdx.x;
  if (tid < DIM) {
    double ps = 0.0, pd = 0.0;
    const float4* w4 = (const float4*)(W0 + tid * DIM);
#pragma unroll
    for (int q = 0; q < DIM / 4; ++q) {
      float4 w = w4[q];
      ps = fma((double)w.x, (double)a0[4 * q + 0], ps);
      ps = fma((double)w.y, (double)a0[4 * q + 1], ps);
      ps = fma((double)w.z, (double)a0[4 * q + 2], ps);
      ps = fma((double)w.w, (double)a0[4 * q + 3], ps);
      pd = fma((double)w.x, (double)a0[DIM + 4 * q + 0], pd);
      pd = fma((double)w.y, (double)a0[DIM + 4 * q + 1], pd);
      pd = fma((double)w.z, (double)a0[DIM + 4 * q + 2], pd);
      pd = fma((double)w.w, (double)a0[DIM + 4 * q + 3], pd);
    }
    p_s[tid] = make_double2(ps, pd);
  }
  __syncthreads();

  const int r = blockIdx.x * 256 + tid;
  if (r >= N_CELLS) return;
  const float4* x4 = (const float4*)(x + (size_t)r * DIM);
  double s0 = 0.0, s1 = 0.0, d0 = 0.0, d1 = 0.0;  // 2-way ILP
#pragma unroll
  for (int q = 0; q < DIM / 4; ++q) {
    float4 v = x4[q];
    double2 p0 = p_s[4 * q + 0], p1 = p_s[4 * q + 1];
    double2 p2 = p_s[4 * q + 2], p3 = p_s[4 * q + 3];
    s0 = fma((double)v.x, p0.x, s0); d0 = fma((double)v.x, p0.y, d0);
    s1 = fma((double)v.y, p1.x, s1); d1 = fma((double)v.y, p1.y, d1);
    s0 = fma((double)v.z, p2.x, s0); d0 = fma((double)v.z, p2.y, d0);
    s1 = fma((double)v.w, p3.x, s1); d1 = fma((double)v.w, p3.y, d1);
  }
  ns[r] = s0 + s1;
  nd[r] = d0 + d1;
}

// Kernel B (wave-per-row, 5 rows/wave):
//   lanes 0..31: e_j = leaky(ns[r]+nd[col_j]) f64; rs = sum; w_j = nv_j*e_j/rs
//   cooperative gather: 16 lanes x float4 = one x row per load (8 dwordx4/row)
//   out[r][lane] = relu( sum_k h[k] * W0[k][lane] )
__global__ __launch_bounds__(256)
void gat_edges(const float* __restrict__ x,
               const int* __restrict__ ecol,
               const float* __restrict__ nv,
               const float* __restrict__ W0,
               const double* __restrict__ ns,
               const double* __restrict__ nd,
               float* __restrict__ out) {
  __shared__ __align__(16) float w_s[4][DEG];
  __shared__ __align__(16) int c_s[4][DEG];
  __shared__ __align__(16) float h_s[4][DIM];

  const int lane = threadIdx.x & 63;
  const int wid = threadIdx.x >> 6;
  const int gwave = blockIdx.x * 4 + wid;
  const int nwaves = gridDim.x * 4;
  const int g = lane >> 4;        // 0..3: which edge of the quad
  const int l = lane & 15;        // 0..15: which float4 of the x row

  // W0 column `lane` in registers (amortized over rows/wave)
  float w0c[DIM];
#pragma unroll
  for (int k = 0; k < DIM; ++k) w0c[k] = W0[k * DIM + lane];

  for (int r = gwave; r < N_CELLS; r += nwaves) {
    // ---- e phase (lanes 0..31), f64 ----
    double e = 0.0;
    int col = 0;
    float nvv = 0.0f;
    if (lane < DEG) {
      col = ecol[r * DEG + lane];
      nvv = nv[r * DEG + lane];
      double z = ns[r] + nd[col];
      e = (z >= 0.0) ? z : NEG_SLOPE * z;
    }
    double rs = e;
#pragma unroll
    for (int m = 16; m >= 1; m >>= 1) rs += __shfl_xor(rs, m, 64);
    if (lane < DEG) {
      w_s[wid][lane] = (float)((double)nvv * (e / rs));
      c_s[wid][lane] = col;
    }

    // ---- cooperative gather: quad g handles edges j = 4q+g ----
    float4 a4 = make_float4(0.f, 0.f, 0.f, 0.f);
#pragma unroll
    for (int q = 0; q < DEG / 4; ++q) {
      int j = 4 * q + g;
      int c = c_s[wid][j];
      float w = w_s[wid][j];
      float4 xv = ((const float4*)x)[(size_t)c * (DIM / 4) + l];
      a4.x = fmaf(w, xv.x, a4.x);
      a4.y = fmaf(w, xv.y, a4.y);
      a4.z = fmaf(w, xv.z, a4.z);
      a4.w = fmaf(w, xv.w, a4.w);
    }
    // reduce across the 4 quads (lanes l, l+16, l+32, l+48)
#pragma unroll
    for (int m = 16; m <= 32; m <<= 1) {
      a4.x += __shfl_xor(a4.x, m, 64);
      a4.y += __shfl_xor(a4.y, m, 64);
      a4.z += __shfl_xor(a4.z, m, 64);
      a4.w += __shfl_xor(a4.w, m, 64);
    }
    if (lane < 16) ((float4*)h_s[wid])[l] = a4;  // h[4l..4l+4)

    // ---- final: out[r][lane] = relu( sum_k h[k] * W0[k][lane] ) ----
    float o = 0.0f;
    const float4* h4p = (const float4*)h_s[wid];
#pragma unroll
    for (int q = 0; q < DIM / 4; ++q) {
      float4 h4 = h4p[q];
      o = fmaf(h4.x, w0c[4 * q + 0], o);
      o = fmaf(h4.y, w0c[4 * q + 1], o);
      o = fmaf(h4.z, w0c[4 * q + 2], o);
      o = fmaf(h4.w, w0c[4 * q + 3], o);
    }
    o = fmaxf(o, 0.0f);
    out[(size_t)r * DIM + lane] = o;
  }
}

extern "C" void kernel_launch(void* const* d_in, const int* in_sizes, int n_in,
                              void* d_out, int out_size, void* d_ws, size_t ws_size,
                              hipStream_t stream) {
  const float* x = (const float*)d_in[0];
  // d_in[1] = edge_rows: known structure repeat(arange(N_CELLS), DEG) — row = edge/DEG
  const int* ecol = (const int*)d_in[2];
  const float* nv = (const float*)d_in[3];
  const float* W0 = (const float*)d_in[4];
  const float* a0 = (const float*)d_in[5];
  float* out = (float*)d_out;

  double* ns = (double*)d_ws;            // 50000 f64
  double* nd = ns + N_CELLS;             // 50000 f64  (800 KB total)

  hipLaunchKernelGGL(gat_nodes, dim3((N_CELLS + 255) / 256), dim3(256), 0, stream,
                     x, W0, a0, ns, nd);
  // 2500 blocks * 4 waves = 10000 waves, 5 rows/wave
  hipLaunchKernelGGL(gat_edges, dim3(2500), dim3(256), 0, stream,
                     x, ecol, nv, W0, ns, nd, out);
}

// Round 4
// 127.519 us; speedup vs baseline: 1.2819x; 1.1491x over previous
//
#include <hip/hip_runtime.h>
#include <hip/hip_fp16.h>

#define N_CELLS 50000
#define DEG 32
#define DIM 64
#define NEG_SLOPE 0.2

// Kernel A: (1) x (f32) -> x2 (fp16) packed copy for low-traffic gathers;
//           (2) ns[r] = x[r].(W0@a_src), nd[r] = x[r].(W0@a_dst), f64 chain
//               (row_sum cancellation amplifies ~1e4x -> f64 required here).
__global__ __launch_bounds__(256)
void gat_prep(const float* __restrict__ x,
              const float* __restrict__ W0,
              const float* __restrict__ a0,
              __half* __restrict__ x2,
              double* __restrict__ ns,
              double* __restrict__ nd) {
  __shared__ double2 p_s[DIM];  // (p_src[i], p_dst[i])

  const int tid = threadIdx.x;
  if (tid < DIM) {
    double ps = 0.0, pd = 0.0;
    const float4* w4 = (const float4*)(W0 + tid * DIM);
#pragma unroll
    for (int q = 0; q < DIM / 4; ++q) {
      float4 w = w4[q];
      ps = fma((double)w.x, (double)a0[4 * q + 0], ps);
      ps = fma((double)w.y, (double)a0[4 * q + 1], ps);
      ps = fma((double)w.z, (double)a0[4 * q + 2], ps);
      ps = fma((double)w.w, (double)a0[4 * q + 3], ps);
      pd = fma((double)w.x, (double)a0[DIM + 4 * q + 0], pd);
      pd = fma((double)w.y, (double)a0[DIM + 4 * q + 1], pd);
      pd = fma((double)w.z, (double)a0[DIM + 4 * q + 2], pd);
      pd = fma((double)w.w, (double)a0[DIM + 4 * q + 3], pd);
    }
    p_s[tid] = make_double2(ps, pd);
  }
  __syncthreads();

  const int gtid = blockIdx.x * 256 + tid;
  const int nthreads = gridDim.x * 256;

  // coalesced f32 -> fp16 conversion
  const float2* xf2 = (const float2*)x;
  __half2* xh2 = (__half2*)x2;
  for (int i = gtid; i < N_CELLS * DIM / 2; i += nthreads) {
    float2 v = xf2[i];
    xh2[i] = __float22half2_rn(v);
  }

  // thread-per-row node dots (x rows are L2/L3-hot from the pass above)
  for (int r = gtid; r < N_CELLS; r += nthreads) {
    const float4* x4 = (const float4*)(x + (size_t)r * DIM);
    double s0 = 0.0, s1 = 0.0, d0 = 0.0, d1 = 0.0;
#pragma unroll
    for (int q = 0; q < DIM / 4; ++q) {
      float4 v = x4[q];
      double2 p0 = p_s[4 * q + 0], p1 = p_s[4 * q + 1];
      double2 p2 = p_s[4 * q + 2], p3 = p_s[4 * q + 3];
      s0 = fma((double)v.x, p0.x, s0); d0 = fma((double)v.x, p0.y, d0);
      s1 = fma((double)v.y, p1.x, s1); d1 = fma((double)v.y, p1.y, d1);
      s0 = fma((double)v.z, p2.x, s0); d0 = fma((double)v.z, p2.y, d0);
      s1 = fma((double)v.w, p3.x, s1); d1 = fma((double)v.w, p3.y, d1);
    }
    ns[r] = s0 + s1;
    nd[r] = d0 + d1;
  }
}

// Kernel B: 2 rows per wave (half = lane>>5 picks the row of a consecutive pair).
//   e-phase: e_j = leaky(ns[r]+nd[col_j]) f64; 5-round xor-reduce gives both
//            rows' row_sums at once; w_j = nv_j*e_j/rs -> LDS.
//   gather:  lane loads fp16x2 dword (features 2*sub, 2*sub+1) of x2[col_j];
//            one instruction serves one edge of BOTH rows. 205 MB L1 traffic
//            over a 6.4 MB footprint (vs 410 MB / 12.8 MB with f32).
//   final:   out[r][lane] = relu( sum_k h[k] * W0[k][lane] ), W0 col in regs.
__global__ __launch_bounds__(256)
void gat_edges(const __half* __restrict__ x2,
               const int* __restrict__ ecol,
               const float* __restrict__ nv,
               const float* __restrict__ W0,
               const double* __restrict__ ns,
               const double* __restrict__ nd,
               float* __restrict__ out) {
  __shared__ __align__(16) float w_s[4][2][DEG];
  __shared__ __align__(16) int c_s[4][2][DEG];
  __shared__ __align__(16) float h_s[4][2][DIM];

  const int lane = threadIdx.x & 63;
  const int wid = threadIdx.x >> 6;
  const int half = lane >> 5;   // which row of the pair
  const int sub = lane & 31;    // edge index / feature-pair index

  // W0 column `lane` in registers
  float w0c[DIM];
#pragma unroll
  for (int k = 0; k < DIM; ++k) w0c[k] = W0[k * DIM + lane];

  const int gwave = blockIdx.x * 4 + wid;
  const int nwaves = gridDim.x * 4;
  const int npairs = N_CELLS / 2;

  for (int p = gwave; p < npairs; p += nwaves) {
    const int r0 = 2 * p;
    const int myrow = r0 + half;

    // ---- e phase: one coalesced 256B load covers both rows' edges ----
    const int eidx = r0 * DEG + lane;   // == myrow*DEG + sub
    const int col = ecol[eidx];
    const float nvv = nv[eidx];
    double z = ns[myrow] + nd[col];
    double e = (z >= 0.0) ? z : NEG_SLOPE * z;
    double rs = e;
#pragma unroll
    for (int m = 16; m >= 1; m >>= 1) rs += __shfl_xor(rs, m, 64);  // per-half sum
    w_s[wid][half][sub] = (float)((double)nvv * (e / rs));
    c_s[wid][half][sub] = col;

    // ---- gather: h[2*sub..2*sub+1] of row `myrow` ----
    const unsigned* xp = (const unsigned*)x2;
    float ax = 0.0f, ay = 0.0f;
#pragma unroll
    for (int j = 0; j < DEG; ++j) {
      int c = c_s[wid][half][j];       // broadcast read, free
      float w = w_s[wid][half][j];
      unsigned pk = xp[(size_t)c * (DIM / 2) + sub];
      float2 xv = __half22float2(*(const __half2*)&pk);
      ax = fmaf(w, xv.x, ax);
      ay = fmaf(w, xv.y, ay);
    }
    ((float2*)h_s[wid][half])[sub] = make_float2(ax, ay);

    // ---- final: both rows' output feature `lane` per lane ----
    float oA = 0.0f, oB = 0.0f;
    const float4* hA = (const float4*)h_s[wid][0];
    const float4* hB = (const float4*)h_s[wid][1];
#pragma unroll
    for (int q = 0; q < DIM / 4; ++q) {
      float4 a = hA[q];  // broadcast
      float4 b = hB[q];
      oA = fmaf(a.x, w0c[4 * q + 0], oA); oB = fmaf(b.x, w0c[4 * q + 0], oB);
      oA = fmaf(a.y, w0c[4 * q + 1], oA); oB = fmaf(b.y, w0c[4 * q + 1], oB);
      oA = fmaf(a.z, w0c[4 * q + 2], oA); oB = fmaf(b.z, w0c[4 * q + 2], oB);
      oA = fmaf(a.w, w0c[4 * q + 3], oA); oB = fmaf(b.w, w0c[4 * q + 3], oB);
    }
    out[(size_t)r0 * DIM + lane] = fmaxf(oA, 0.0f);
    out[(size_t)(r0 + 1) * DIM + lane] = fmaxf(oB, 0.0f);
  }
}

extern "C" void kernel_launch(void* const* d_in, const int* in_sizes, int n_in,
                              void* d_out, int out_size, void* d_ws, size_t ws_size,
                              hipStream_t stream) {
  const float* x = (const float*)d_in[0];
  // d_in[1] = edge_rows: known structure repeat(arange(N_CELLS), DEG) — row = edge/DEG
  const int* ecol = (const int*)d_in[2];
  const float* nv = (const float*)d_in[3];
  const float* W0 = (const float*)d_in[4];
  const float* a0 = (const float*)d_in[5];
  float* out = (float*)d_out;

  // ws layout: x2 (6.4 MB fp16) | ns (400 KB f64) | nd (400 KB f64)
  __half* x2 = (__half*)d_ws;
  double* ns = (double*)((char*)d_ws + (size_t)N_CELLS * DIM * sizeof(__half));
  double* nd = ns + N_CELLS;

  hipLaunchKernelGGL(gat_prep, dim3(512), dim3(256), 0, stream,
                     x, W0, a0, x2, ns, nd);
  // 2500 blocks * 4 waves = 10000 waves, 2.5 row-pairs per wave
  hipLaunchKernelGGL(gat_edges, dim3(2500), dim3(256), 0, stream,
                     x2, ecol, nv, W0, ns, nd, out);
}